// Round 16
// baseline (2796.976 us; speedup 1.0000x reference)
//
#include <hip/hip_runtime.h>
#include <math.h>
#include <stdint.h>

#define BLOCK 256
#define PPB 64     // problems per block (16 per wave)
#define HP 132     // h row stride per prob
#define WCOLS 2136 // per-wave h region floats (16*132 + 3*8 swizzle pad)
#define NTILES 56  // 4 (W0) + 16*3 (W1..3) + 4 (W4) tiles of 1024 floats

typedef float v2f __attribute__((ext_vector_type(2)));

__device__ __forceinline__ v2f mkv2(float a, float b) {
    v2f r; r.x = a; r.y = b; return r;
}
__device__ __forceinline__ v2f pkfma(v2f a, v2f b, v2f c) {
#if __has_builtin(__builtin_elementwise_fma)
    return __builtin_elementwise_fma(a, b, c);
#else
    return mkv2(fmaf(a.x, b.x, c.x), fmaf(a.y, b.y, c.y));
#endif
}
__device__ __forceinline__ float f4el(const float4& v, int r) {
    return (r == 0) ? v.x : (r == 1) ? v.y : (r == 2) ? v.z : v.w;
}
__device__ __forceinline__ int col_base(int p) { return p * HP + ((p >> 2) << 3); }

// prep: 56 contiguous tiles of 1024 floats:
// tiles 0..3 W0 (col-permuted: col = q*8+half*4+jl at word r*128+half*64+q*4+jl),
// 4..19 W1, 20..35 W2, 36..51 W3, 52..55 W4 (32x32, permuted col = s*8+half*4+jl)
__global__ void prep_kernel(const float* __restrict__ W0, const float* __restrict__ W1,
                            const float* __restrict__ W2, const float* __restrict__ W3,
                            const float* __restrict__ W4, const float* __restrict__ b4,
                            float* __restrict__ Wt, float* __restrict__ b4p) {
    const int d = blockIdx.x * blockDim.x + threadIdx.x;
    if (d < NTILES * 1024) {
        const int t = d >> 10, w = d & 1023;
        float v;
        if (t < 52) {
            const int r = w >> 7, rem = w & 127;
            const int half = rem >> 6, q = (rem >> 2) & 15, jl = rem & 3;
            const int col = q * 8 + half * 4 + jl;
            if (t < 4)       { const int k = t * 8 + r;        v = (k < 27) ? W0[k * 128 + col] : 0.f; }
            else if (t < 20) { const int k = (t - 4) * 8 + r;  v = W1[k * 128 + col]; }
            else if (t < 36) { const int k = (t - 20) * 8 + r; v = W2[k * 128 + col]; }
            else             { const int k = (t - 36) * 8 + r; v = W3[k * 128 + col]; }
        } else {
            const int r = w >> 5, rem = w & 31;
            const int half = (rem >> 4) & 1, s = (rem >> 2) & 3, jl = rem & 3;
            const int col = s * 8 + half * 4 + jl;
            const int k = (t - 52) * 32 + r;
            v = (col < 25) ? W4[k * 25 + col] : 0.f;
        }
        Wt[d] = v;
    }
    if (d < 32) b4p[d] = (d < 25) ? b4[d] : 0.f;
}

// 4-row FMA batch, weights from LDS tile (rows r0..r0+3), h from LDS
__device__ __forceinline__ void batch4(const float* wt, int r0, int cg,
                                       const float* hg, int k0,
                                       v2f* __restrict__ acc) {
    float4 h4[4];
#pragma unroll
    for (int p = 0; p < 4; ++p) h4[p] = *(const float4*)(hg + p * HP + k0);
    float4 w0[4], w1[4];
#pragma unroll
    for (int r = 0; r < 4; ++r) {
        w0[r] = *(const float4*)(wt + (r0 + r) * 128 + cg * 4);
        w1[r] = *(const float4*)(wt + (r0 + r) * 128 + 64 + cg * 4);
    }
#pragma unroll
    for (int r = 0; r < 4; ++r) {
        const v2f wa = mkv2(w0[r].x, w0[r].y), wb2 = mkv2(w0[r].z, w0[r].w);
        const v2f wc = mkv2(w1[r].x, w1[r].y), wd = mkv2(w1[r].z, w1[r].w);
#pragma unroll
        for (int p = 0; p < 4; ++p) {
            const float hv = f4el(h4[p], r);
            const v2f hh = mkv2(hv, hv);
            acc[p * 4 + 0] = pkfma(hh, wa, acc[p * 4 + 0]);
            acc[p * 4 + 1] = pkfma(hh, wb2, acc[p * 4 + 1]);
            acc[p * 4 + 2] = pkfma(hh, wc, acc[p * 4 + 2]);
            acc[p * 4 + 3] = pkfma(hh, wd, acc[p * 4 + 3]);
        }
    }
}

// LDS state slots: 0..8 J, 9..11 up, 12..14 dx, 15..17 dg, 18..20 xo,
// 21 nopt, 22..24 rw (cached tf(xopt)·xopt+off -> no final eval)
__global__ __launch_bounds__(BLOCK)
__attribute__((amdgpu_num_vgpr(128))) void snarf_kernel(
    const float* __restrict__ xin, const float* __restrict__ bone_pts,
    const float* __restrict__ transforms, const float* __restrict__ delta_tf,
    const float* __restrict__ Wt, const float* __restrict__ b0,
    const float* __restrict__ b1, const float* __restrict__ b2,
    const float* __restrict__ b3, const float* __restrict__ b4p,
    float* __restrict__ out, int Npts) {
    __shared__ float hL[4 * WCOLS];   // 34176 B swizzled h[prob][k]
    __shared__ float stL[25 * PPB];   // 6400 B solver state
    __shared__ float wb[2][1024];     // 8192 B weight tile double-buffer
    __shared__ int flags[4];          // (total 48784 B)
    const int tid = threadIdx.x;
    const int wid = tid >> 6;
    const int lane = tid & 63;
    const int p16 = lane & 15;
    const int sq = lane >> 4;
    const int cg = lane >> 2;
    const int gg = lane & 3;
    const int M = Npts * 6;
    const int m = blockIdx.x * PPB + wid * 16 + p16;
    const int mc = (m < M) ? m : (M - 1);
    const int n = mc / 6;
    const int i = mc - n * 6;

    float* hWv = &hL[wid * WCOLS];
    const float* hg = hWv + gg * 536;
    float* hwr = hWv + gg * 536 + 8 * cg;
    float* hq = hWv + col_base(p16);
    volatile float* st = &stL[wid * 16 + p16];
#define STS(idx) st[(idx) * PPB]

    const float tx = xin[n * 3 + 0], ty = xin[n * 3 + 1], tz = xin[n * 3 + 2];

    // ---- init candidate (duplicated across sq; bitwise identical)
    float xk0, xk1, xk2;
    if (i < 5) {
        float dprev = -1.0f;
        int jprev = -1;
        for (int r = 0; r <= i; ++r) {
            float bd = 3.4028235e38f;
            int bj = 0;
            for (int j = 0; j < 24; ++j) {
                const float ax = tx - bone_pts[j * 3 + 0];
                const float ay = ty - bone_pts[j * 3 + 1];
                const float az = tz - bone_pts[j * 3 + 2];
                const float d = sqrtf(ax * ax + ay * ay + az * az);
                const bool taken = (d < dprev) || (d == dprev && j <= jprev);
                if (!taken && d < bd) { bd = d; bj = j; }
            }
            dprev = bd;
            jprev = bj;
        }
        const float* T = delta_tf + jprev * 16;
        xk0 = fmaf(T[0], tx, fmaf(T[1], ty, fmaf(T[2], tz, T[3])));
        xk1 = fmaf(T[4], tx, fmaf(T[5], ty, fmaf(T[6], tz, T[7])));
        xk2 = fmaf(T[8], tx, fmaf(T[9], ty, fmaf(T[10], tz, T[11])));
    } else {
        xk0 = tx; xk1 = ty; xk2 = tz;
    }

    float gx0 = 0.f, gx1 = 0.f, gx2 = 0.f;
    bool mask = (m < M);

    // stage tile 0 into buf 0 (register round-trip staging as in R12)
    int cur = 0;
    *(float4*)(&wb[0][0] + tid * 4) = *(const float4*)(Wt + tid * 4);
    __syncthreads();

    for (int step = -1; step < 8; ++step) {
        bool m3 = mask;
        if (step >= 0) {
            __syncthreads();
            if ((flags[0] | flags[1] | flags[2] | flags[3]) == 0) break;
            if (m3) {
                const float u0 = STS(9), u1 = STS(10), u2 = STS(11);
                STS(12) = u0; STS(13) = u1; STS(14) = u2;
                xk0 += u0; xk1 += u1; xk2 += u2;
            }
        }
        const float cx0 = xk0, cx1 = xk1, cx2 = xk2;

        // ---- positional encoding, split by scale (sq owns scale 1<<sq), fast trig
        {
            const float f = (float)(1 << sq);
            float sx, cxv, sy, cyv, sz, czv;
            __sincosf(f * cx0, &sx, &cxv);
            __sincosf(f * cx1, &sy, &cyv);
            __sincosf(f * cx2, &sz, &czv);
            if (sq == 0) { hq[0] = cx0; hq[1] = cx1; hq[2] = cx2; }
            const int sb = 3 + sq * 3;
            hq[sb + 0] = sx;  hq[sb + 1] = sy;  hq[sb + 2] = sz;
            hq[sb + 12] = cxv; hq[sb + 13] = cyv; hq[sb + 14] = czv;
            if (sq == 3) {
                hq[27] = 0.f; hq[28] = 0.f; hq[29] = 0.f; hq[30] = 0.f; hq[31] = 0.f;
            }
        }

        __builtin_amdgcn_s_setprio(1);
        int gt = 0;  // tile id within this eval (0..55)
        // ---- 4 main layers from LDS tiles (tiles 0..51)
#pragma unroll 1
        for (int L = 0; L < 4; ++L) {
            const int NT = (L == 0) ? 4 : 16;
            const float* bc = ((L == 0) ? b0 : (L == 1) ? b1 : (L == 2) ? b2 : b3) + 8 * cg;
            v2f acc[16];
            {
                const float4 b0v = *(const float4*)(bc);
                const float4 b1v = *(const float4*)(bc + 4);
#pragma unroll
                for (int p = 0; p < 4; ++p) {
                    acc[p * 4 + 0] = mkv2(b0v.x, b0v.y);
                    acc[p * 4 + 1] = mkv2(b0v.z, b0v.w);
                    acc[p * 4 + 2] = mkv2(b1v.x, b1v.y);
                    acc[p * 4 + 3] = mkv2(b1v.z, b1v.w);
                }
            }
#pragma unroll 1
            for (int t = 0; t < NT; ++t) {
                // T14 async-stage: load next tile early (regs), write to LDS late
                const float4 stg = *(const float4*)(Wt + (gt + 1) * 1024 + tid * 4);
                batch4(&wb[cur][0], 0, cg, hg, t * 8, acc);
                batch4(&wb[cur][0], 4, cg, hg, t * 8 + 4, acc);
                *(float4*)(&wb[cur ^ 1][0] + tid * 4) = stg;
                __syncthreads();
                cur ^= 1;
                ++gt;
            }
            // writeback, p-order staggered by cg&3 (16-way -> 4-way bank spread)
#pragma unroll
            for (int q = 0; q < 4; ++q) {
                const int p = (q + (cg & 3)) & 3;
                float4 o0, o1;
                o0.x = fmaxf(acc[p * 4 + 0].x, 0.f); o0.y = fmaxf(acc[p * 4 + 0].y, 0.f);
                o0.z = fmaxf(acc[p * 4 + 1].x, 0.f); o0.w = fmaxf(acc[p * 4 + 1].y, 0.f);
                o1.x = fmaxf(acc[p * 4 + 2].x, 0.f); o1.y = fmaxf(acc[p * 4 + 2].y, 0.f);
                o1.z = fmaxf(acc[p * 4 + 3].x, 0.f); o1.w = fmaxf(acc[p * 4 + 3].y, 0.f);
                *(float4*)(hwr + p * HP) = o0;
                *(float4*)(hwr + p * HP + 4) = o1;
            }
        }

        // ---- output layer: tiles 52..55 (32 rows x 32 permuted cols each)
        {
            v2f la[4];
            const float4 bb0 = *(const float4*)(b4p + 8 * sq);
            const float4 bb1 = *(const float4*)(b4p + 8 * sq + 4);
            la[0] = mkv2(bb0.x, bb0.y); la[1] = mkv2(bb0.z, bb0.w);
            la[2] = mkv2(bb1.x, bb1.y); la[3] = mkv2(bb1.z, bb1.w);
#pragma unroll 1
            for (int t = 0; t < 4; ++t) {
                const int nt = (t < 3) ? (53 + t) : 0;  // wrap: last stages tile 0
                const float4 stg = *(const float4*)(Wt + nt * 1024 + tid * 4);
                const float* wt = &wb[cur][0];
#pragma unroll 2
                for (int kb = 0; kb < 8; ++kb) {
                    const float4 h4 = *(const float4*)(hq + t * 32 + kb * 4);
#pragma unroll
                    for (int r = 0; r < 4; ++r) {
                        const float4 w0 = *(const float4*)(wt + (kb * 4 + r) * 32 + sq * 4);
                        const float4 w1 = *(const float4*)(wt + (kb * 4 + r) * 32 + 16 + sq * 4);
                        const float hv = f4el(h4, r);
                        const v2f hh = mkv2(hv, hv);
                        la[0] = pkfma(hh, mkv2(w0.x, w0.y), la[0]);
                        la[1] = pkfma(hh, mkv2(w0.z, w0.w), la[1]);
                        la[2] = pkfma(hh, mkv2(w1.x, w1.y), la[2]);
                        la[3] = pkfma(hh, mkv2(w1.z, w1.w), la[3]);
                    }
                }
                *(float4*)(&wb[cur ^ 1][0] + tid * 4) = stg;
                __syncthreads();
                cur ^= 1;
            }
            __builtin_amdgcn_s_setprio(0);
            float4 o0, o1;
            o0.x = la[0].x; o0.y = la[0].y; o0.z = la[1].x; o0.w = la[1].y;
            o1.x = la[2].x; o1.y = la[2].y; o1.z = la[3].x; o1.w = la[3].y;
            *(float4*)(hq + 8 * sq) = o0;
            *(float4*)(hq + 8 * sq + 4) = o1;
        }

        // ---- read 25 logits (dup x4)
        float l25[25];
        {
            const float4 r0 = *(const float4*)(hq + 0);
            const float4 r1 = *(const float4*)(hq + 4);
            const float4 r2 = *(const float4*)(hq + 8);
            const float4 r3 = *(const float4*)(hq + 12);
            const float4 r4 = *(const float4*)(hq + 16);
            const float4 r5 = *(const float4*)(hq + 20);
            l25[0] = r0.x; l25[1] = r0.y; l25[2] = r0.z; l25[3] = r0.w;
            l25[4] = r1.x; l25[5] = r1.y; l25[6] = r1.z; l25[7] = r1.w;
            l25[8] = r2.x; l25[9] = r2.y; l25[10] = r2.z; l25[11] = r2.w;
            l25[12] = r3.x; l25[13] = r3.y; l25[14] = r3.z; l25[15] = r3.w;
            l25[16] = r4.x; l25[17] = r4.y; l25[18] = r4.z; l25[19] = r4.w;
            l25[20] = r5.x; l25[21] = r5.y; l25[22] = r5.z; l25[23] = r5.w;
            l25[24] = hq[24];
        }

        // softmax(5 * logits) over 25, fast exp
        float zm = -3.4028235e38f;
#pragma unroll
        for (int j = 0; j < 25; ++j) {
            l25[j] = 5.0f * l25[j];
            zm = fmaxf(zm, l25[j]);
        }
        float ssum = 0.f;
#pragma unroll
        for (int j = 0; j < 25; ++j) {
            l25[j] = __expf(l25[j] - zm);
            ssum += l25[j];
        }
        const float inv = 1.0f / ssum;

        // ---- blend, row-split across sq: lane sq<3 computes output row sq
        float r0, r1, r2;
        {
            const int rs = (sq < 3) ? sq : 0;
            float tfr0 = 0.f, tfr1 = 0.f, tfr2 = 0.f, tfr3 = 0.f;
#pragma unroll
            for (int j = 0; j < 24; ++j) {
                const float wj = l25[j] * inv;
                const float* T = transforms + j * 16 + rs * 4;
                tfr0 = fmaf(wj, T[0], tfr0);
                tfr1 = fmaf(wj, T[1], tfr1);
                tfr2 = fmaf(wj, T[2], tfr2);
                tfr3 = fmaf(wj, T[3], tfr3);
            }
            {
                const float wj = l25[24] * inv;  // identity transform diag
                if (rs == 0) tfr0 += wj;
                else if (rs == 1) tfr1 += wj;
                else tfr2 += wj;
            }
            const float rr = fmaf(tfr0, cx0, fmaf(tfr1, cx1, fmaf(tfr2, cx2, tfr3)));
            if (sq < 3) hq[29 + sq] = rr;  // scratch rows (re-zeroed each pe)
            asm volatile("s_waitcnt lgkmcnt(0)" ::: "memory");
            __builtin_amdgcn_sched_barrier(0);
            r0 = hq[29]; r1 = hq[30]; r2 = hq[31];
            asm volatile("s_waitcnt lgkmcnt(0)" ::: "memory");
            __builtin_amdgcn_sched_barrier(0);
        }

        const float g0 = r0 - tx, g1 = r1 - ty, g2 = r2 - tz;

        if (step == -1) {
            gx0 = g0; gx1 = g1; gx2 = g2;
            const float gn = sqrtf(g0 * g0 + g1 * g1 + g2 * g2);
            STS(21) = gn;
            STS(9) = -g0; STS(10) = -g1; STS(11) = -g2;
            STS(18) = xk0; STS(19) = xk1; STS(20) = xk2;
            STS(22) = r0; STS(23) = r1; STS(24) = r2;
            STS(12) = 0.f; STS(13) = 0.f; STS(14) = 0.f;
            STS(15) = 0.f; STS(16) = 0.f; STS(17) = 0.f;
            STS(0) = 1.f; STS(1) = 0.f; STS(2) = 0.f;
            STS(3) = 0.f; STS(4) = 1.f; STS(5) = 0.f;
            STS(6) = 0.f; STS(7) = 0.f; STS(8) = 1.f;
        } else {
            float J00 = STS(0), J01 = STS(1), J02 = STS(2);
            float J10 = STS(3), J11 = STS(4), J12 = STS(5);
            float J20 = STS(6), J21 = STS(7), J22 = STS(8);
            const float dx0 = STS(12), dx1 = STS(13), dx2 = STS(14);
            float dg0 = STS(15), dg1 = STS(16), dg2 = STS(17);
            float nopt = STS(21);
            if (m3) {
                dg0 = g0 - gx0; dg1 = g1 - gx1; dg2 = g2 - gx2;
                gx0 += dg0; gx1 += dg1; gx2 += dg2;
                STS(15) = dg0; STS(16) = dg1; STS(17) = dg2;
            }
            const float gn = sqrtf(gx0 * gx0 + gx1 * gx1 + gx2 * gx2);
            const bool better = gn < nopt;
            if (better) {
                nopt = gn;
                STS(21) = gn;
                STS(18) = xk0; STS(19) = xk1; STS(20) = xk2;
                STS(22) = r0; STS(23) = r1; STS(24) = r2;
            }
            mask = (nopt > 1e-5f) && (gn < 1.0f) && (m < M);

            const float v0 = dx0 * J00 + dx1 * J10 + dx2 * J20;
            const float v1 = dx0 * J01 + dx1 * J11 + dx2 * J21;
            const float v2 = dx0 * J02 + dx1 * J12 + dx2 * J22;
            const float Jd0 = J00 * dg0 + J01 * dg1 + J02 * dg2;
            const float Jd1 = J10 * dg0 + J11 * dg1 + J12 * dg2;
            const float Jd2 = J20 * dg0 + J21 * dg1 + J22 * dg2;
            const float a0 = dx0 - Jd0, a1 = dx1 - Jd1, a2 = dx2 - Jd2;
            float bden = v0 * dg0 + v1 * dg1 + v2 * dg2;
            bden += (bden >= 0.f) ? 1e-6f : -1e-6f;
            if (mask) {
                const float q0 = a0 / bden, q1 = a1 / bden, q2 = a2 / bden;
                J00 = fmaf(q0, v0, J00); J01 = fmaf(q0, v1, J01); J02 = fmaf(q0, v2, J02);
                J10 = fmaf(q1, v0, J10); J11 = fmaf(q1, v1, J11); J12 = fmaf(q1, v2, J12);
                J20 = fmaf(q2, v0, J20); J21 = fmaf(q2, v1, J21); J22 = fmaf(q2, v2, J22);
                STS(0) = J00; STS(1) = J01; STS(2) = J02;
                STS(3) = J10; STS(4) = J11; STS(5) = J12;
                STS(6) = J20; STS(7) = J21; STS(8) = J22;
            }
            if (m3) {
                STS(9) = -(J00 * gx0 + J01 * gx1 + J02 * gx2);
                STS(10) = -(J10 * gx0 + J11 * gx1 + J12 * gx2);
                STS(11) = -(J20 * gx0 + J21 * gx1 + J22 * gx2);
            }
        }
        // block-exit flags (read after the barrier at next eval top)
        {
            const unsigned long long b = __ballot(mask);
            if (lane == 0) flags[wid] = (b != 0ull) ? 1 : 0;
        }
    }

    // ---- epilogue: all outputs from cached state (no final eval)
    if (sq == 0 && m < M) {
        const float nopt = STS(21);
        out[(size_t)m * 3 + 0] = STS(22);
        out[(size_t)m * 3 + 1] = STS(23);
        out[(size_t)m * 3 + 2] = STS(24);
        float* xopt_out = out + (size_t)M * 3;
        xopt_out[(size_t)m * 3 + 0] = STS(18);
        xopt_out[(size_t)m * 3 + 1] = STS(19);
        xopt_out[(size_t)m * 3 + 2] = STS(20);
        out[(size_t)M * 6 + m] = nopt;
        out[(size_t)M * 7 + m] = (nopt < 1e-5f) ? 1.0f : 0.0f;
    }
#undef STS
}

extern "C" void kernel_launch(void* const* d_in, const int* in_sizes, int n_in,
                              void* d_out, int out_size, void* d_ws, size_t ws_size,
                              hipStream_t stream) {
    const float* x = (const float*)d_in[0];
    const float* bone_pts = (const float*)d_in[1];
    const float* transforms = (const float*)d_in[2];
    const float* delta_tf = (const float*)d_in[3];
    const float* W0 = (const float*)d_in[4];
    const float* b0 = (const float*)d_in[5];
    const float* W1 = (const float*)d_in[6];
    const float* b1 = (const float*)d_in[7];
    const float* W2 = (const float*)d_in[8];
    const float* b2 = (const float*)d_in[9];
    const float* W3 = (const float*)d_in[10];
    const float* b3 = (const float*)d_in[11];
    const float* W4 = (const float*)d_in[12];
    const float* b4 = (const float*)d_in[13];
    float* out = (float*)d_out;

    float* Wt = (float*)d_ws;          // 56*1024 floats (tiled weights)
    float* b4p = Wt + NTILES * 1024;   // 32 floats

    prep_kernel<<<(NTILES * 1024 + 255) / 256, 256, 0, stream>>>(
        W0, W1, W2, W3, W4, b4, Wt, b4p);

    const int Npts = in_sizes[0] / 3;
    const int M = Npts * 6;
    const int blocks = (M + PPB - 1) / PPB;
    snarf_kernel<<<blocks, BLOCK, 0, stream>>>(
        x, bone_pts, transforms, delta_tf, Wt, b0, b1, b2, b3, b4p, out, Npts);
}

// Round 17
// 2757.649 us; speedup vs baseline: 1.0143x; 1.0143x over previous
//
#include <hip/hip_runtime.h>
#include <math.h>
#include <stdint.h>

#define BLOCK 256
#define PPB 64     // problems per block (16 per wave)
#define HP 132     // h row stride per prob
#define WCOLS 2136 // per-wave h region floats (16*132 + 3*8 swizzle pad)
#define NTILES 56  // 4 (W0) + 16*3 (W1..3) + 4 (W4) tiles of 1024 floats

typedef float v2f __attribute__((ext_vector_type(2)));

__device__ __forceinline__ v2f mkv2(float a, float b) {
    v2f r; r.x = a; r.y = b; return r;
}
__device__ __forceinline__ v2f pkfma(v2f a, v2f b, v2f c) {
#if __has_builtin(__builtin_elementwise_fma)
    return __builtin_elementwise_fma(a, b, c);
#else
    return mkv2(fmaf(a.x, b.x, c.x), fmaf(a.y, b.y, c.y));
#endif
}
__device__ __forceinline__ float f4el(const float4& v, int r) {
    return (r == 0) ? v.x : (r == 1) ? v.y : (r == 2) ? v.z : v.w;
}
__device__ __forceinline__ int col_base(int p) { return p * HP + ((p >> 2) << 3); }

// prep: 56 contiguous tiles of 1024 floats:
// tiles 0..3 W0 (col-permuted: col = q*8+half*4+jl at word r*128+half*64+q*4+jl),
// 4..19 W1, 20..35 W2, 36..51 W3, 52..55 W4 (32x32, permuted col = s*8+half*4+jl)
__global__ void prep_kernel(const float* __restrict__ W0, const float* __restrict__ W1,
                            const float* __restrict__ W2, const float* __restrict__ W3,
                            const float* __restrict__ W4, const float* __restrict__ b4,
                            float* __restrict__ Wt, float* __restrict__ b4p) {
    const int d = blockIdx.x * blockDim.x + threadIdx.x;
    if (d < NTILES * 1024) {
        const int t = d >> 10, w = d & 1023;
        float v;
        if (t < 52) {
            const int r = w >> 7, rem = w & 127;
            const int half = rem >> 6, q = (rem >> 2) & 15, jl = rem & 3;
            const int col = q * 8 + half * 4 + jl;
            if (t < 4)       { const int k = t * 8 + r;        v = (k < 27) ? W0[k * 128 + col] : 0.f; }
            else if (t < 20) { const int k = (t - 4) * 8 + r;  v = W1[k * 128 + col]; }
            else if (t < 36) { const int k = (t - 20) * 8 + r; v = W2[k * 128 + col]; }
            else             { const int k = (t - 36) * 8 + r; v = W3[k * 128 + col]; }
        } else {
            const int r = w >> 5, rem = w & 31;
            const int half = (rem >> 4) & 1, s = (rem >> 2) & 3, jl = rem & 3;
            const int col = s * 8 + half * 4 + jl;
            const int k = (t - 52) * 32 + r;
            v = (col < 25) ? W4[k * 25 + col] : 0.f;
        }
        Wt[d] = v;
    }
    if (d < 32) b4p[d] = (d < 25) ? b4[d] : 0.f;
}

// 4-row FMA batch, weights from LDS tile (rows r0..r0+3), h from LDS
__device__ __forceinline__ void batch4(const float* wt, int r0, int cg,
                                       const float* hg, int k0,
                                       v2f* __restrict__ acc) {
    float4 h4[4];
#pragma unroll
    for (int p = 0; p < 4; ++p) h4[p] = *(const float4*)(hg + p * HP + k0);
    float4 w0[4], w1[4];
#pragma unroll
    for (int r = 0; r < 4; ++r) {
        w0[r] = *(const float4*)(wt + (r0 + r) * 128 + cg * 4);
        w1[r] = *(const float4*)(wt + (r0 + r) * 128 + 64 + cg * 4);
    }
#pragma unroll
    for (int r = 0; r < 4; ++r) {
        const v2f wa = mkv2(w0[r].x, w0[r].y), wb2 = mkv2(w0[r].z, w0[r].w);
        const v2f wc = mkv2(w1[r].x, w1[r].y), wd = mkv2(w1[r].z, w1[r].w);
#pragma unroll
        for (int p = 0; p < 4; ++p) {
            const float hv = f4el(h4[p], r);
            const v2f hh = mkv2(hv, hv);
            acc[p * 4 + 0] = pkfma(hh, wa, acc[p * 4 + 0]);
            acc[p * 4 + 1] = pkfma(hh, wb2, acc[p * 4 + 1]);
            acc[p * 4 + 2] = pkfma(hh, wc, acc[p * 4 + 2]);
            acc[p * 4 + 3] = pkfma(hh, wd, acc[p * 4 + 3]);
        }
    }
}

// LDS state slots: 0..8 J, 9..11 up, 12..14 dx, 15..17 dg, 18..20 xo,
// 21 nopt, 22..24 rw (cached tf(xopt)·xopt+off -> no final eval)
__global__ __launch_bounds__(BLOCK)
__attribute__((amdgpu_num_vgpr(128))) void snarf_kernel(
    const float* __restrict__ xin, const float* __restrict__ bone_pts,
    const float* __restrict__ transforms, const float* __restrict__ delta_tf,
    const float* __restrict__ Wt, const float* __restrict__ b0,
    const float* __restrict__ b1, const float* __restrict__ b2,
    const float* __restrict__ b3, const float* __restrict__ b4p,
    float* __restrict__ out, int Npts) {
    __shared__ float hL[4 * WCOLS];   // 34176 B swizzled h[prob][k]
    __shared__ float stL[25 * PPB];   // 6400 B solver state
    __shared__ float wb[2][1024];     // 8192 B weight tile double-buffer
    __shared__ int flags[4];          // (total 48784 B)
    const int tid = threadIdx.x;
    const int wid = tid >> 6;
    const int lane = tid & 63;
    const int p16 = lane & 15;
    const int sq = lane >> 4;
    const int cg = lane >> 2;
    const int gg = lane & 3;
    const int M = Npts * 6;
    const int m = blockIdx.x * PPB + wid * 16 + p16;
    const int mc = (m < M) ? m : (M - 1);
    const int n = mc / 6;
    const int i = mc - n * 6;

    float* hWv = &hL[wid * WCOLS];
    const float* hg = hWv + gg * 536;
    float* hwr = hWv + gg * 536 + 8 * cg;
    float* hq = hWv + col_base(p16);
    volatile float* st = &stL[wid * 16 + p16];
#define STS(idx) st[(idx) * PPB]

    const float tx = xin[n * 3 + 0], ty = xin[n * 3 + 1], tz = xin[n * 3 + 2];

    // ---- init candidate (duplicated across sq; bitwise identical)
    float xk0, xk1, xk2;
    if (i < 5) {
        float dprev = -1.0f;
        int jprev = -1;
        for (int r = 0; r <= i; ++r) {
            float bd = 3.4028235e38f;
            int bj = 0;
            for (int j = 0; j < 24; ++j) {
                const float ax = tx - bone_pts[j * 3 + 0];
                const float ay = ty - bone_pts[j * 3 + 1];
                const float az = tz - bone_pts[j * 3 + 2];
                const float d = sqrtf(ax * ax + ay * ay + az * az);
                const bool taken = (d < dprev) || (d == dprev && j <= jprev);
                if (!taken && d < bd) { bd = d; bj = j; }
            }
            dprev = bd;
            jprev = bj;
        }
        const float* T = delta_tf + jprev * 16;
        xk0 = fmaf(T[0], tx, fmaf(T[1], ty, fmaf(T[2], tz, T[3])));
        xk1 = fmaf(T[4], tx, fmaf(T[5], ty, fmaf(T[6], tz, T[7])));
        xk2 = fmaf(T[8], tx, fmaf(T[9], ty, fmaf(T[10], tz, T[11])));
    } else {
        xk0 = tx; xk1 = ty; xk2 = tz;
    }

    float gx0 = 0.f, gx1 = 0.f, gx2 = 0.f;
    bool mask = (m < M);

    // stage tile 0 into buf 0 (register round-trip staging)
    int cur = 0;
    *(float4*)(&wb[0][0] + tid * 4) = *(const float4*)(Wt + tid * 4);
    __syncthreads();

    for (int step = -1; step < 8; ++step) {
        bool m3 = mask;
        if (step >= 0) {
            __syncthreads();
            if ((flags[0] | flags[1] | flags[2] | flags[3]) == 0) break;
            if (m3) {
                const float u0 = STS(9), u1 = STS(10), u2 = STS(11);
                STS(12) = u0; STS(13) = u1; STS(14) = u2;
                xk0 += u0; xk1 += u1; xk2 += u2;
            }
        }

        // wave-skip: a fully-converged wave keeps the barrier/staging lockstep
        // (56 syncthreads, same as active path) but does no math
        if (__ballot(mask) == 0ull) {
            int gt = 0;
#pragma unroll 1
            for (int t = 0; t < NTILES; ++t) {
                const int nt = (gt + 1 < NTILES) ? (gt + 1) : 0;
                const float4 stg = *(const float4*)(Wt + nt * 1024 + tid * 4);
                *(float4*)(&wb[cur ^ 1][0] + tid * 4) = stg;
                __syncthreads();
                cur ^= 1;
                ++gt;
            }
            // flags already 0 for this wave; keep writing for consistency
            if (lane == 0) flags[wid] = 0;
            continue;
        }

        const float cx0 = xk0, cx1 = xk1, cx2 = xk2;

        // ---- positional encoding, split by scale (sq owns scale 1<<sq)
        {
            const float f = (float)(1 << sq);
            float sx, cxv, sy, cyv, sz, czv;
            sincosf(f * cx0, &sx, &cxv);
            sincosf(f * cx1, &sy, &cyv);
            sincosf(f * cx2, &sz, &czv);
            if (sq == 0) { hq[0] = cx0; hq[1] = cx1; hq[2] = cx2; }
            const int sb = 3 + sq * 3;
            hq[sb + 0] = sx;  hq[sb + 1] = sy;  hq[sb + 2] = sz;
            hq[sb + 12] = cxv; hq[sb + 13] = cyv; hq[sb + 14] = czv;
            if (sq == 3) {
                hq[27] = 0.f; hq[28] = 0.f; hq[29] = 0.f; hq[30] = 0.f; hq[31] = 0.f;
            }
        }

        __builtin_amdgcn_s_setprio(1);
        int gt = 0;  // tile id within this eval (0..55)
        // ---- 4 main layers from LDS tiles (tiles 0..51)
#pragma unroll 1
        for (int L = 0; L < 4; ++L) {
            const int NT = (L == 0) ? 4 : 16;
            const float* bc = ((L == 0) ? b0 : (L == 1) ? b1 : (L == 2) ? b2 : b3) + 8 * cg;
            v2f acc[16];
            {
                const float4 b0v = *(const float4*)(bc);
                const float4 b1v = *(const float4*)(bc + 4);
#pragma unroll
                for (int p = 0; p < 4; ++p) {
                    acc[p * 4 + 0] = mkv2(b0v.x, b0v.y);
                    acc[p * 4 + 1] = mkv2(b0v.z, b0v.w);
                    acc[p * 4 + 2] = mkv2(b1v.x, b1v.y);
                    acc[p * 4 + 3] = mkv2(b1v.z, b1v.w);
                }
            }
#pragma unroll 1
            for (int t = 0; t < NT; ++t) {
                // async-stage: load next tile early (regs), write to LDS late
                const float4 stg = *(const float4*)(Wt + (gt + 1) * 1024 + tid * 4);
                batch4(&wb[cur][0], 0, cg, hg, t * 8, acc);
                batch4(&wb[cur][0], 4, cg, hg, t * 8 + 4, acc);
                *(float4*)(&wb[cur ^ 1][0] + tid * 4) = stg;
                __syncthreads();
                cur ^= 1;
                ++gt;
            }
            // writeback, p staggered by (cg>>2)&3: colliding lanes (same
            // 8cg mod 32) get distinct p -> banks split 0/4/8/12
#pragma unroll
            for (int q = 0; q < 4; ++q) {
                const int p = (q + (cg >> 2)) & 3;
                float4 o0, o1;
                o0.x = fmaxf(acc[p * 4 + 0].x, 0.f); o0.y = fmaxf(acc[p * 4 + 0].y, 0.f);
                o0.z = fmaxf(acc[p * 4 + 1].x, 0.f); o0.w = fmaxf(acc[p * 4 + 1].y, 0.f);
                o1.x = fmaxf(acc[p * 4 + 2].x, 0.f); o1.y = fmaxf(acc[p * 4 + 2].y, 0.f);
                o1.z = fmaxf(acc[p * 4 + 3].x, 0.f); o1.w = fmaxf(acc[p * 4 + 3].y, 0.f);
                *(float4*)(hwr + p * HP) = o0;
                *(float4*)(hwr + p * HP + 4) = o1;
            }
        }

        // ---- output layer: tiles 52..55 (32 rows x 32 permuted cols each)
        {
            v2f la[4];
            const float4 bb0 = *(const float4*)(b4p + 8 * sq);
            const float4 bb1 = *(const float4*)(b4p + 8 * sq + 4);
            la[0] = mkv2(bb0.x, bb0.y); la[1] = mkv2(bb0.z, bb0.w);
            la[2] = mkv2(bb1.x, bb1.y); la[3] = mkv2(bb1.z, bb1.w);
#pragma unroll 1
            for (int t = 0; t < 4; ++t) {
                const int nt = (t < 3) ? (53 + t) : 0;  // wrap: last stages tile 0
                const float4 stg = *(const float4*)(Wt + nt * 1024 + tid * 4);
                const float* wt = &wb[cur][0];
#pragma unroll 2
                for (int kb = 0; kb < 8; ++kb) {
                    const float4 h4 = *(const float4*)(hq + t * 32 + kb * 4);
#pragma unroll
                    for (int r = 0; r < 4; ++r) {
                        const float4 w0 = *(const float4*)(wt + (kb * 4 + r) * 32 + sq * 4);
                        const float4 w1 = *(const float4*)(wt + (kb * 4 + r) * 32 + 16 + sq * 4);
                        const float hv = f4el(h4, r);
                        const v2f hh = mkv2(hv, hv);
                        la[0] = pkfma(hh, mkv2(w0.x, w0.y), la[0]);
                        la[1] = pkfma(hh, mkv2(w0.z, w0.w), la[1]);
                        la[2] = pkfma(hh, mkv2(w1.x, w1.y), la[2]);
                        la[3] = pkfma(hh, mkv2(w1.z, w1.w), la[3]);
                    }
                }
                *(float4*)(&wb[cur ^ 1][0] + tid * 4) = stg;
                __syncthreads();
                cur ^= 1;
            }
            __builtin_amdgcn_s_setprio(0);
            float4 o0, o1;
            o0.x = la[0].x; o0.y = la[0].y; o0.z = la[1].x; o0.w = la[1].y;
            o1.x = la[2].x; o1.y = la[2].y; o1.z = la[3].x; o1.w = la[3].y;
            *(float4*)(hq + 8 * sq) = o0;
            *(float4*)(hq + 8 * sq + 4) = o1;
        }

        // ---- read 25 logits (dup x4)
        float l25[25];
        {
            const float4 r0 = *(const float4*)(hq + 0);
            const float4 r1 = *(const float4*)(hq + 4);
            const float4 r2 = *(const float4*)(hq + 8);
            const float4 r3 = *(const float4*)(hq + 12);
            const float4 r4 = *(const float4*)(hq + 16);
            const float4 r5 = *(const float4*)(hq + 20);
            l25[0] = r0.x; l25[1] = r0.y; l25[2] = r0.z; l25[3] = r0.w;
            l25[4] = r1.x; l25[5] = r1.y; l25[6] = r1.z; l25[7] = r1.w;
            l25[8] = r2.x; l25[9] = r2.y; l25[10] = r2.z; l25[11] = r2.w;
            l25[12] = r3.x; l25[13] = r3.y; l25[14] = r3.z; l25[15] = r3.w;
            l25[16] = r4.x; l25[17] = r4.y; l25[18] = r4.z; l25[19] = r4.w;
            l25[20] = r5.x; l25[21] = r5.y; l25[22] = r5.z; l25[23] = r5.w;
            l25[24] = hq[24];
        }

        // softmax(5 * logits) over 25
        float zm = -3.4028235e38f;
#pragma unroll
        for (int j = 0; j < 25; ++j) {
            l25[j] = 5.0f * l25[j];
            zm = fmaxf(zm, l25[j]);
        }
        float ssum = 0.f;
#pragma unroll
        for (int j = 0; j < 25; ++j) {
            l25[j] = expf(l25[j] - zm);
            ssum += l25[j];
        }
        const float inv = 1.0f / ssum;

        float tf[12];
#pragma unroll
        for (int r = 0; r < 12; ++r) tf[r] = 0.f;
#pragma unroll
        for (int j = 0; j < 24; ++j) {
            const float wj = l25[j] * inv;
            const float* T = transforms + j * 16;
#pragma unroll
            for (int r = 0; r < 12; ++r) tf[r] = fmaf(wj, T[r], tf[r]);
        }
        {
            const float wj = l25[24] * inv;
            tf[0] += wj; tf[5] += wj; tf[10] += wj;
        }
        const float r0 = fmaf(tf[0], cx0, fmaf(tf[1], cx1, fmaf(tf[2], cx2, tf[3])));
        const float r1 = fmaf(tf[4], cx0, fmaf(tf[5], cx1, fmaf(tf[6], cx2, tf[7])));
        const float r2 = fmaf(tf[8], cx0, fmaf(tf[9], cx1, fmaf(tf[10], cx2, tf[11])));

        const float g0 = r0 - tx, g1 = r1 - ty, g2 = r2 - tz;

        if (step == -1) {
            gx0 = g0; gx1 = g1; gx2 = g2;
            const float gn = sqrtf(g0 * g0 + g1 * g1 + g2 * g2);
            STS(21) = gn;
            STS(9) = -g0; STS(10) = -g1; STS(11) = -g2;
            STS(18) = xk0; STS(19) = xk1; STS(20) = xk2;
            STS(22) = r0; STS(23) = r1; STS(24) = r2;
            STS(12) = 0.f; STS(13) = 0.f; STS(14) = 0.f;
            STS(15) = 0.f; STS(16) = 0.f; STS(17) = 0.f;
            STS(0) = 1.f; STS(1) = 0.f; STS(2) = 0.f;
            STS(3) = 0.f; STS(4) = 1.f; STS(5) = 0.f;
            STS(6) = 0.f; STS(7) = 0.f; STS(8) = 1.f;
        } else {
            float J00 = STS(0), J01 = STS(1), J02 = STS(2);
            float J10 = STS(3), J11 = STS(4), J12 = STS(5);
            float J20 = STS(6), J21 = STS(7), J22 = STS(8);
            const float dx0 = STS(12), dx1 = STS(13), dx2 = STS(14);
            float dg0 = STS(15), dg1 = STS(16), dg2 = STS(17);
            float nopt = STS(21);
            if (m3) {
                dg0 = g0 - gx0; dg1 = g1 - gx1; dg2 = g2 - gx2;
                gx0 += dg0; gx1 += dg1; gx2 += dg2;
                STS(15) = dg0; STS(16) = dg1; STS(17) = dg2;
            }
            const float gn = sqrtf(gx0 * gx0 + gx1 * gx1 + gx2 * gx2);
            const bool better = gn < nopt;
            if (better) {
                nopt = gn;
                STS(21) = gn;
                STS(18) = xk0; STS(19) = xk1; STS(20) = xk2;
                STS(22) = r0; STS(23) = r1; STS(24) = r2;
            }
            mask = (nopt > 1e-5f) && (gn < 1.0f) && (m < M);

            const float v0 = dx0 * J00 + dx1 * J10 + dx2 * J20;
            const float v1 = dx0 * J01 + dx1 * J11 + dx2 * J21;
            const float v2 = dx0 * J02 + dx1 * J12 + dx2 * J22;
            const float Jd0 = J00 * dg0 + J01 * dg1 + J02 * dg2;
            const float Jd1 = J10 * dg0 + J11 * dg1 + J12 * dg2;
            const float Jd2 = J20 * dg0 + J21 * dg1 + J22 * dg2;
            const float a0 = dx0 - Jd0, a1 = dx1 - Jd1, a2 = dx2 - Jd2;
            float bden = v0 * dg0 + v1 * dg1 + v2 * dg2;
            bden += (bden >= 0.f) ? 1e-6f : -1e-6f;
            if (mask) {
                const float q0 = a0 / bden, q1 = a1 / bden, q2 = a2 / bden;
                J00 = fmaf(q0, v0, J00); J01 = fmaf(q0, v1, J01); J02 = fmaf(q0, v2, J02);
                J10 = fmaf(q1, v0, J10); J11 = fmaf(q1, v1, J11); J12 = fmaf(q1, v2, J12);
                J20 = fmaf(q2, v0, J20); J21 = fmaf(q2, v1, J21); J22 = fmaf(q2, v2, J22);
                STS(0) = J00; STS(1) = J01; STS(2) = J02;
                STS(3) = J10; STS(4) = J11; STS(5) = J12;
                STS(6) = J20; STS(7) = J21; STS(8) = J22;
            }
            if (m3) {
                STS(9) = -(J00 * gx0 + J01 * gx1 + J02 * gx2);
                STS(10) = -(J10 * gx0 + J11 * gx1 + J12 * gx2);
                STS(11) = -(J20 * gx0 + J21 * gx1 + J22 * gx2);
            }
        }
        // block-exit flags (read after the barrier at next eval top)
        {
            const unsigned long long b = __ballot(mask);
            if (lane == 0) flags[wid] = (b != 0ull) ? 1 : 0;
        }
    }

    // ---- epilogue: all outputs from cached state (no final eval)
    if (sq == 0 && m < M) {
        const float nopt = STS(21);
        out[(size_t)m * 3 + 0] = STS(22);
        out[(size_t)m * 3 + 1] = STS(23);
        out[(size_t)m * 3 + 2] = STS(24);
        float* xopt_out = out + (size_t)M * 3;
        xopt_out[(size_t)m * 3 + 0] = STS(18);
        xopt_out[(size_t)m * 3 + 1] = STS(19);
        xopt_out[(size_t)m * 3 + 2] = STS(20);
        out[(size_t)M * 6 + m] = nopt;
        out[(size_t)M * 7 + m] = (nopt < 1e-5f) ? 1.0f : 0.0f;
    }
#undef STS
}

extern "C" void kernel_launch(void* const* d_in, const int* in_sizes, int n_in,
                              void* d_out, int out_size, void* d_ws, size_t ws_size,
                              hipStream_t stream) {
    const float* x = (const float*)d_in[0];
    const float* bone_pts = (const float*)d_in[1];
    const float* transforms = (const float*)d_in[2];
    const float* delta_tf = (const float*)d_in[3];
    const float* W0 = (const float*)d_in[4];
    const float* b0 = (const float*)d_in[5];
    const float* W1 = (const float*)d_in[6];
    const float* b1 = (const float*)d_in[7];
    const float* W2 = (const float*)d_in[8];
    const float* b2 = (const float*)d_in[9];
    const float* W3 = (const float*)d_in[10];
    const float* b3 = (const float*)d_in[11];
    const float* W4 = (const float*)d_in[12];
    const float* b4 = (const float*)d_in[13];
    float* out = (float*)d_out;

    float* Wt = (float*)d_ws;          // 56*1024 floats (tiled weights)
    float* b4p = Wt + NTILES * 1024;   // 32 floats

    prep_kernel<<<(NTILES * 1024 + 255) / 256, 256, 0, stream>>>(
        W0, W1, W2, W3, W4, b4, Wt, b4p);

    const int Npts = in_sizes[0] / 3;
    const int M = Npts * 6;
    const int blocks = (M + PPB - 1) / PPB;
    snarf_kernel<<<blocks, BLOCK, 0, stream>>>(
        x, bone_pts, transforms, delta_tf, Wt, b0, b1, b2, b3, b4p, out, Npts);
}

// Round 18
// 1722.751 us; speedup vs baseline: 1.6236x; 1.6007x over previous
//
#include <hip/hip_runtime.h>
#include <math.h>
#include <stdint.h>

#define BLOCK 256
#define PPB 64     // problems per block (16 per wave)
#define HP 132     // h row stride per prob
#define WCOLS 2136 // per-wave h region floats (16*132 + 3*8 swizzle pad)
#define NTILES 56  // 4 (W0) + 16*3 (W1..3) + 4 (W4) tiles of 1024 floats

typedef float v2f __attribute__((ext_vector_type(2)));

__device__ __forceinline__ v2f mkv2(float a, float b) {
    v2f r; r.x = a; r.y = b; return r;
}
__device__ __forceinline__ v2f pkfma(v2f a, v2f b, v2f c) {
#if __has_builtin(__builtin_elementwise_fma)
    return __builtin_elementwise_fma(a, b, c);
#else
    return mkv2(fmaf(a.x, b.x, c.x), fmaf(a.y, b.y, c.y));
#endif
}
__device__ __forceinline__ float f4el(const float4& v, int r) {
    return (r == 0) ? v.x : (r == 1) ? v.y : (r == 2) ? v.z : v.w;
}
__device__ __forceinline__ int col_base(int p) { return p * HP + ((p >> 2) << 3); }

// prep: 56 contiguous tiles of 1024 floats:
// tiles 0..3 W0 (col-permuted: col = q*8+half*4+jl at word r*128+half*64+q*4+jl),
// 4..19 W1, 20..35 W2, 36..51 W3, 52..55 W4 (32x32, permuted col = s*8+half*4+jl)
__global__ void prep_kernel(const float* __restrict__ W0, const float* __restrict__ W1,
                            const float* __restrict__ W2, const float* __restrict__ W3,
                            const float* __restrict__ W4, const float* __restrict__ b4,
                            float* __restrict__ Wt, float* __restrict__ b4p) {
    const int d = blockIdx.x * blockDim.x + threadIdx.x;
    if (d < NTILES * 1024) {
        const int t = d >> 10, w = d & 1023;
        float v;
        if (t < 52) {
            const int r = w >> 7, rem = w & 127;
            const int half = rem >> 6, q = (rem >> 2) & 15, jl = rem & 3;
            const int col = q * 8 + half * 4 + jl;
            if (t < 4)       { const int k = t * 8 + r;        v = (k < 27) ? W0[k * 128 + col] : 0.f; }
            else if (t < 20) { const int k = (t - 4) * 8 + r;  v = W1[k * 128 + col]; }
            else if (t < 36) { const int k = (t - 20) * 8 + r; v = W2[k * 128 + col]; }
            else             { const int k = (t - 36) * 8 + r; v = W3[k * 128 + col]; }
        } else {
            const int r = w >> 5, rem = w & 31;
            const int half = (rem >> 4) & 1, s = (rem >> 2) & 3, jl = rem & 3;
            const int col = s * 8 + half * 4 + jl;
            const int k = (t - 52) * 32 + r;
            v = (col < 25) ? W4[k * 25 + col] : 0.f;
        }
        Wt[d] = v;
    }
    if (d < 32) b4p[d] = (d < 25) ? b4[d] : 0.f;
}

// 4-row FMA batch, weights from LDS tile (rows r0..r0+3), h from LDS
__device__ __forceinline__ void batch4(const float* wt, int r0, int cg,
                                       const float* hg, int k0,
                                       v2f* __restrict__ acc) {
    float4 h4[4];
#pragma unroll
    for (int p = 0; p < 4; ++p) h4[p] = *(const float4*)(hg + p * HP + k0);
    float4 w0[4], w1[4];
#pragma unroll
    for (int r = 0; r < 4; ++r) {
        w0[r] = *(const float4*)(wt + (r0 + r) * 128 + cg * 4);
        w1[r] = *(const float4*)(wt + (r0 + r) * 128 + 64 + cg * 4);
    }
#pragma unroll
    for (int r = 0; r < 4; ++r) {
        const v2f wa = mkv2(w0[r].x, w0[r].y), wb2 = mkv2(w0[r].z, w0[r].w);
        const v2f wc = mkv2(w1[r].x, w1[r].y), wd = mkv2(w1[r].z, w1[r].w);
#pragma unroll
        for (int p = 0; p < 4; ++p) {
            const float hv = f4el(h4[p], r);
            const v2f hh = mkv2(hv, hv);
            acc[p * 4 + 0] = pkfma(hh, wa, acc[p * 4 + 0]);
            acc[p * 4 + 1] = pkfma(hh, wb2, acc[p * 4 + 1]);
            acc[p * 4 + 2] = pkfma(hh, wc, acc[p * 4 + 2]);
            acc[p * 4 + 3] = pkfma(hh, wd, acc[p * 4 + 3]);
        }
    }
}

// LDS state slots: 0..8 J, 9..11 up, 12..14 dx, 15..17 dg, 18..20 xo,
// 21 nopt, 22..24 rw (cached tf(xopt)·xopt+off -> no final eval)
__global__ __launch_bounds__(BLOCK)
__attribute__((amdgpu_num_vgpr(128))) void snarf_kernel(
    const float* __restrict__ xin, const float* __restrict__ bone_pts,
    const float* __restrict__ transforms, const float* __restrict__ delta_tf,
    const float* __restrict__ Wt, const float* __restrict__ b0,
    const float* __restrict__ b1, const float* __restrict__ b2,
    const float* __restrict__ b3, const float* __restrict__ b4p,
    float* __restrict__ out, int Npts) {
    __shared__ float hL[4 * WCOLS];   // 34176 B swizzled h[prob][k]
    __shared__ float stL[25 * PPB];   // 6400 B solver state
    __shared__ float wb[2][1024];     // 8192 B weight tile double-buffer
    __shared__ int flags[4];          // (total 48784 B)
    const int tid = threadIdx.x;
    const int wid = tid >> 6;
    const int lane = tid & 63;
    const int p16 = lane & 15;
    const int sq = lane >> 4;
    const int cg = lane >> 2;
    const int gg = lane & 3;
    const int M = Npts * 6;
    const int m = blockIdx.x * PPB + wid * 16 + p16;
    const int mc = (m < M) ? m : (M - 1);
    const int n = mc / 6;
    const int i = mc - n * 6;

    float* hWv = &hL[wid * WCOLS];
    const float* hg = hWv + gg * 536;
    float* hwr = hWv + gg * 536 + 8 * cg;
    float* hq = hWv + col_base(p16);
    volatile float* st = &stL[wid * 16 + p16];
#define STS(idx) st[(idx) * PPB]

    const float tx = xin[n * 3 + 0], ty = xin[n * 3 + 1], tz = xin[n * 3 + 2];

    // ---- init candidate (duplicated across sq; bitwise identical)
    float xk0, xk1, xk2;
    if (i < 5) {
        float dprev = -1.0f;
        int jprev = -1;
        for (int r = 0; r <= i; ++r) {
            float bd = 3.4028235e38f;
            int bj = 0;
            for (int j = 0; j < 24; ++j) {
                const float ax = tx - bone_pts[j * 3 + 0];
                const float ay = ty - bone_pts[j * 3 + 1];
                const float az = tz - bone_pts[j * 3 + 2];
                const float d = sqrtf(ax * ax + ay * ay + az * az);
                const bool taken = (d < dprev) || (d == dprev && j <= jprev);
                if (!taken && d < bd) { bd = d; bj = j; }
            }
            dprev = bd;
            jprev = bj;
        }
        const float* T = delta_tf + jprev * 16;
        xk0 = fmaf(T[0], tx, fmaf(T[1], ty, fmaf(T[2], tz, T[3])));
        xk1 = fmaf(T[4], tx, fmaf(T[5], ty, fmaf(T[6], tz, T[7])));
        xk2 = fmaf(T[8], tx, fmaf(T[9], ty, fmaf(T[10], tz, T[11])));
    } else {
        xk0 = tx; xk1 = ty; xk2 = tz;
    }

    float gx0 = 0.f, gx1 = 0.f, gx2 = 0.f;
    bool mask = (m < M);

    // stage tile 0 into buf 0 (register round-trip staging)
    int cur = 0;
    *(float4*)(&wb[0][0] + tid * 4) = *(const float4*)(Wt + tid * 4);
    __syncthreads();

    for (int step = -1; step < 8; ++step) {
        bool m3 = mask;
        if (step >= 0) {
            __syncthreads();
            if ((flags[0] | flags[1] | flags[2] | flags[3]) == 0) break;
            if (m3) {
                const float u0 = STS(9), u1 = STS(10), u2 = STS(11);
                STS(12) = u0; STS(13) = u1; STS(14) = u2;
                xk0 += u0; xk1 += u1; xk2 += u2;
            }
        }

        // wave-skip: fully-converged wave keeps barrier/staging lockstep
        // (same staged-tile sequence 1..55,0 and same 56 barriers) but no math
        if (__ballot(mask) == 0ull) {
#pragma unroll 1
            for (int t = 0; t < NTILES; ++t) {
                const int nt = (t + 1 < NTILES) ? (t + 1) : 0;
                const float4 stg = *(const float4*)(Wt + nt * 1024 + tid * 4);
                *(float4*)(&wb[cur ^ 1][0] + tid * 4) = stg;
                __syncthreads();
                cur ^= 1;
            }
            if (lane == 0) flags[wid] = 0;
            continue;
        }

        const float cx0 = xk0, cx1 = xk1, cx2 = xk2;

        // ---- positional encoding, split by scale (sq owns scale 1<<sq), HW trig
        {
            const float f = (float)(1 << sq);
            float sx, cxv, sy, cyv, sz, czv;
            __sincosf(f * cx0, &sx, &cxv);
            __sincosf(f * cx1, &sy, &cyv);
            __sincosf(f * cx2, &sz, &czv);
            if (sq == 0) { hq[0] = cx0; hq[1] = cx1; hq[2] = cx2; }
            const int sb = 3 + sq * 3;
            hq[sb + 0] = sx;  hq[sb + 1] = sy;  hq[sb + 2] = sz;
            hq[sb + 12] = cxv; hq[sb + 13] = cyv; hq[sb + 14] = czv;
            if (sq == 3) {
                hq[27] = 0.f; hq[28] = 0.f; hq[29] = 0.f; hq[30] = 0.f; hq[31] = 0.f;
            }
        }

        __builtin_amdgcn_s_setprio(1);
        int gt = 0;  // tile id within this eval (0..55)
        // ---- 4 main layers from LDS tiles (tiles 0..51)
#pragma unroll 1
        for (int L = 0; L < 4; ++L) {
            const int NT = (L == 0) ? 4 : 16;
            const float* bc = ((L == 0) ? b0 : (L == 1) ? b1 : (L == 2) ? b2 : b3) + 8 * cg;
            v2f acc[16];
            {
                const float4 b0v = *(const float4*)(bc);
                const float4 b1v = *(const float4*)(bc + 4);
#pragma unroll
                for (int p = 0; p < 4; ++p) {
                    acc[p * 4 + 0] = mkv2(b0v.x, b0v.y);
                    acc[p * 4 + 1] = mkv2(b0v.z, b0v.w);
                    acc[p * 4 + 2] = mkv2(b1v.x, b1v.y);
                    acc[p * 4 + 3] = mkv2(b1v.z, b1v.w);
                }
            }
#pragma unroll 1
            for (int t = 0; t < NT; ++t) {
                // async-stage: load next tile early (regs), write to LDS late
                const float4 stg = *(const float4*)(Wt + (gt + 1) * 1024 + tid * 4);
                batch4(&wb[cur][0], 0, cg, hg, t * 8, acc);
                batch4(&wb[cur][0], 4, cg, hg, t * 8 + 4, acc);
                *(float4*)(&wb[cur ^ 1][0] + tid * 4) = stg;
                __syncthreads();
                cur ^= 1;
                ++gt;
            }
            // writeback (static p order)
#pragma unroll
            for (int p = 0; p < 4; ++p) {
                float4 o0, o1;
                o0.x = fmaxf(acc[p * 4 + 0].x, 0.f); o0.y = fmaxf(acc[p * 4 + 0].y, 0.f);
                o0.z = fmaxf(acc[p * 4 + 1].x, 0.f); o0.w = fmaxf(acc[p * 4 + 1].y, 0.f);
                o1.x = fmaxf(acc[p * 4 + 2].x, 0.f); o1.y = fmaxf(acc[p * 4 + 2].y, 0.f);
                o1.z = fmaxf(acc[p * 4 + 3].x, 0.f); o1.w = fmaxf(acc[p * 4 + 3].y, 0.f);
                *(float4*)(hwr + p * HP) = o0;
                *(float4*)(hwr + p * HP + 4) = o1;
            }
        }

        // ---- output layer: tiles 52..55 (32 rows x 32 permuted cols each)
        {
            v2f la[4];
            const float4 bb0 = *(const float4*)(b4p + 8 * sq);
            const float4 bb1 = *(const float4*)(b4p + 8 * sq + 4);
            la[0] = mkv2(bb0.x, bb0.y); la[1] = mkv2(bb0.z, bb0.w);
            la[2] = mkv2(bb1.x, bb1.y); la[3] = mkv2(bb1.z, bb1.w);
#pragma unroll 1
            for (int t = 0; t < 4; ++t) {
                const int nt = (t < 3) ? (53 + t) : 0;  // wrap: last stages tile 0
                const float4 stg = *(const float4*)(Wt + nt * 1024 + tid * 4);
                const float* wt = &wb[cur][0];
#pragma unroll 2
                for (int kb = 0; kb < 8; ++kb) {
                    const float4 h4 = *(const float4*)(hq + t * 32 + kb * 4);
#pragma unroll
                    for (int r = 0; r < 4; ++r) {
                        const float4 w0 = *(const float4*)(wt + (kb * 4 + r) * 32 + sq * 4);
                        const float4 w1 = *(const float4*)(wt + (kb * 4 + r) * 32 + 16 + sq * 4);
                        const float hv = f4el(h4, r);
                        const v2f hh = mkv2(hv, hv);
                        la[0] = pkfma(hh, mkv2(w0.x, w0.y), la[0]);
                        la[1] = pkfma(hh, mkv2(w0.z, w0.w), la[1]);
                        la[2] = pkfma(hh, mkv2(w1.x, w1.y), la[2]);
                        la[3] = pkfma(hh, mkv2(w1.z, w1.w), la[3]);
                    }
                }
                *(float4*)(&wb[cur ^ 1][0] + tid * 4) = stg;
                __syncthreads();
                cur ^= 1;
            }
            __builtin_amdgcn_s_setprio(0);
            float4 o0, o1;
            o0.x = la[0].x; o0.y = la[0].y; o0.z = la[1].x; o0.w = la[1].y;
            o1.x = la[2].x; o1.y = la[2].y; o1.z = la[3].x; o1.w = la[3].y;
            *(float4*)(hq + 8 * sq) = o0;
            *(float4*)(hq + 8 * sq + 4) = o1;
        }

        // ---- read 25 logits (dup x4)
        float l25[25];
        {
            const float4 r0 = *(const float4*)(hq + 0);
            const float4 r1 = *(const float4*)(hq + 4);
            const float4 r2 = *(const float4*)(hq + 8);
            const float4 r3 = *(const float4*)(hq + 12);
            const float4 r4 = *(const float4*)(hq + 16);
            const float4 r5 = *(const float4*)(hq + 20);
            l25[0] = r0.x; l25[1] = r0.y; l25[2] = r0.z; l25[3] = r0.w;
            l25[4] = r1.x; l25[5] = r1.y; l25[6] = r1.z; l25[7] = r1.w;
            l25[8] = r2.x; l25[9] = r2.y; l25[10] = r2.z; l25[11] = r2.w;
            l25[12] = r3.x; l25[13] = r3.y; l25[14] = r3.z; l25[15] = r3.w;
            l25[16] = r4.x; l25[17] = r4.y; l25[18] = r4.z; l25[19] = r4.w;
            l25[20] = r5.x; l25[21] = r5.y; l25[22] = r5.z; l25[23] = r5.w;
            l25[24] = hq[24];
        }

        // softmax(5 * logits) over 25, HW exp
        float zm = -3.4028235e38f;
#pragma unroll
        for (int j = 0; j < 25; ++j) {
            l25[j] = 5.0f * l25[j];
            zm = fmaxf(zm, l25[j]);
        }
        float ssum = 0.f;
#pragma unroll
        for (int j = 0; j < 25; ++j) {
            l25[j] = __expf(l25[j] - zm);
            ssum += l25[j];
        }
        const float inv = 1.0f / ssum;

        float tf[12];
#pragma unroll
        for (int r = 0; r < 12; ++r) tf[r] = 0.f;
#pragma unroll
        for (int j = 0; j < 24; ++j) {
            const float wj = l25[j] * inv;
            const float* T = transforms + j * 16;
#pragma unroll
            for (int r = 0; r < 12; ++r) tf[r] = fmaf(wj, T[r], tf[r]);
        }
        {
            const float wj = l25[24] * inv;
            tf[0] += wj; tf[5] += wj; tf[10] += wj;
        }
        const float r0 = fmaf(tf[0], cx0, fmaf(tf[1], cx1, fmaf(tf[2], cx2, tf[3])));
        const float r1 = fmaf(tf[4], cx0, fmaf(tf[5], cx1, fmaf(tf[6], cx2, tf[7])));
        const float r2 = fmaf(tf[8], cx0, fmaf(tf[9], cx1, fmaf(tf[10], cx2, tf[11])));

        const float g0 = r0 - tx, g1 = r1 - ty, g2 = r2 - tz;

        if (step == -1) {
            gx0 = g0; gx1 = g1; gx2 = g2;
            const float gn = sqrtf(g0 * g0 + g1 * g1 + g2 * g2);
            STS(21) = gn;
            STS(9) = -g0; STS(10) = -g1; STS(11) = -g2;
            STS(18) = xk0; STS(19) = xk1; STS(20) = xk2;
            STS(22) = r0; STS(23) = r1; STS(24) = r2;
            STS(12) = 0.f; STS(13) = 0.f; STS(14) = 0.f;
            STS(15) = 0.f; STS(16) = 0.f; STS(17) = 0.f;
            STS(0) = 1.f; STS(1) = 0.f; STS(2) = 0.f;
            STS(3) = 0.f; STS(4) = 1.f; STS(5) = 0.f;
            STS(6) = 0.f; STS(7) = 0.f; STS(8) = 1.f;
        } else {
            float J00 = STS(0), J01 = STS(1), J02 = STS(2);
            float J10 = STS(3), J11 = STS(4), J12 = STS(5);
            float J20 = STS(6), J21 = STS(7), J22 = STS(8);
            const float dx0 = STS(12), dx1 = STS(13), dx2 = STS(14);
            float dg0 = STS(15), dg1 = STS(16), dg2 = STS(17);
            float nopt = STS(21);
            if (m3) {
                dg0 = g0 - gx0; dg1 = g1 - gx1; dg2 = g2 - gx2;
                gx0 += dg0; gx1 += dg1; gx2 += dg2;
                STS(15) = dg0; STS(16) = dg1; STS(17) = dg2;
            }
            const float gn = sqrtf(gx0 * gx0 + gx1 * gx1 + gx2 * gx2);
            const bool better = gn < nopt;
            if (better) {
                nopt = gn;
                STS(21) = gn;
                STS(18) = xk0; STS(19) = xk1; STS(20) = xk2;
                STS(22) = r0; STS(23) = r1; STS(24) = r2;
            }
            mask = (nopt > 1e-5f) && (gn < 1.0f) && (m < M);

            const float v0 = dx0 * J00 + dx1 * J10 + dx2 * J20;
            const float v1 = dx0 * J01 + dx1 * J11 + dx2 * J21;
            const float v2 = dx0 * J02 + dx1 * J12 + dx2 * J22;
            const float Jd0 = J00 * dg0 + J01 * dg1 + J02 * dg2;
            const float Jd1 = J10 * dg0 + J11 * dg1 + J12 * dg2;
            const float Jd2 = J20 * dg0 + J21 * dg1 + J22 * dg2;
            const float a0 = dx0 - Jd0, a1 = dx1 - Jd1, a2 = dx2 - Jd2;
            float bden = v0 * dg0 + v1 * dg1 + v2 * dg2;
            bden += (bden >= 0.f) ? 1e-6f : -1e-6f;
            if (mask) {
                const float q0 = a0 / bden, q1 = a1 / bden, q2 = a2 / bden;
                J00 = fmaf(q0, v0, J00); J01 = fmaf(q0, v1, J01); J02 = fmaf(q0, v2, J02);
                J10 = fmaf(q1, v0, J10); J11 = fmaf(q1, v1, J11); J12 = fmaf(q1, v2, J12);
                J20 = fmaf(q2, v0, J20); J21 = fmaf(q2, v1, J21); J22 = fmaf(q2, v2, J22);
                STS(0) = J00; STS(1) = J01; STS(2) = J02;
                STS(3) = J10; STS(4) = J11; STS(5) = J12;
                STS(6) = J20; STS(7) = J21; STS(8) = J22;
            }
            if (m3) {
                STS(9) = -(J00 * gx0 + J01 * gx1 + J02 * gx2);
                STS(10) = -(J10 * gx0 + J11 * gx1 + J12 * gx2);
                STS(11) = -(J20 * gx0 + J21 * gx1 + J22 * gx2);
            }
        }
        // block-exit flags (read after the barrier at next eval top)
        {
            const unsigned long long b = __ballot(mask);
            if (lane == 0) flags[wid] = (b != 0ull) ? 1 : 0;
        }
    }

    // ---- epilogue: all outputs from cached state (no final eval)
    if (sq == 0 && m < M) {
        const float nopt = STS(21);
        out[(size_t)m * 3 + 0] = STS(22);
        out[(size_t)m * 3 + 1] = STS(23);
        out[(size_t)m * 3 + 2] = STS(24);
        float* xopt_out = out + (size_t)M * 3;
        xopt_out[(size_t)m * 3 + 0] = STS(18);
        xopt_out[(size_t)m * 3 + 1] = STS(19);
        xopt_out[(size_t)m * 3 + 2] = STS(20);
        out[(size_t)M * 6 + m] = nopt;
        out[(size_t)M * 7 + m] = (nopt < 1e-5f) ? 1.0f : 0.0f;
    }
#undef STS
}

extern "C" void kernel_launch(void* const* d_in, const int* in_sizes, int n_in,
                              void* d_out, int out_size, void* d_ws, size_t ws_size,
                              hipStream_t stream) {
    const float* x = (const float*)d_in[0];
    const float* bone_pts = (const float*)d_in[1];
    const float* transforms = (const float*)d_in[2];
    const float* delta_tf = (const float*)d_in[3];
    const float* W0 = (const float*)d_in[4];
    const float* b0 = (const float*)d_in[5];
    const float* W1 = (const float*)d_in[6];
    const float* b1 = (const float*)d_in[7];
    const float* W2 = (const float*)d_in[8];
    const float* b2 = (const float*)d_in[9];
    const float* W3 = (const float*)d_in[10];
    const float* b3 = (const float*)d_in[11];
    const float* W4 = (const float*)d_in[12];
    const float* b4 = (const float*)d_in[13];
    float* out = (float*)d_out;

    float* Wt = (float*)d_ws;          // 56*1024 floats (tiled weights)
    float* b4p = Wt + NTILES * 1024;   // 32 floats

    prep_kernel<<<(NTILES * 1024 + 255) / 256, 256, 0, stream>>>(
        W0, W1, W2, W3, W4, b4, Wt, b4p);

    const int Npts = in_sizes[0] / 3;
    const int M = Npts * 6;
    const int blocks = (M + PPB - 1) / PPB;
    snarf_kernel<<<blocks, BLOCK, 0, stream>>>(
        x, bone_pts, transforms, delta_tf, Wt, b0, b1, b2, b3, b4p, out, Npts);
}

// Round 19
// 1671.603 us; speedup vs baseline: 1.6732x; 1.0306x over previous
//
#include <hip/hip_runtime.h>
#include <math.h>
#include <stdint.h>

#define BLOCK 256
#define PPB 64     // problems per block (16 per wave)
#define HP 132     // h row stride per prob
#define WCOLS 2136 // per-wave h region floats (16*132 + 3*8 swizzle pad)
#define NTILES 56  // 4 (W0) + 16*3 (W1..3) + 4 (W4) tiles of 1024 floats

typedef float v2f __attribute__((ext_vector_type(2)));

__device__ __forceinline__ v2f mkv2(float a, float b) {
    v2f r; r.x = a; r.y = b; return r;
}
__device__ __forceinline__ v2f pkfma(v2f a, v2f b, v2f c) {
#if __has_builtin(__builtin_elementwise_fma)
    return __builtin_elementwise_fma(a, b, c);
#else
    return mkv2(fmaf(a.x, b.x, c.x), fmaf(a.y, b.y, c.y));
#endif
}
__device__ __forceinline__ float f4el(const float4& v, int r) {
    return (r == 0) ? v.x : (r == 1) ? v.y : (r == 2) ? v.z : v.w;
}
__device__ __forceinline__ int col_base(int p) { return p * HP + ((p >> 2) << 3); }

// prep: 56 contiguous tiles of 1024 floats:
// tiles 0..3 W0 (col-permuted: col = q*8+half*4+jl at word r*128+half*64+q*4+jl),
// 4..19 W1, 20..35 W2, 36..51 W3, 52..55 W4 (32x32, permuted col = s*8+half*4+jl)
__global__ void prep_kernel(const float* __restrict__ W0, const float* __restrict__ W1,
                            const float* __restrict__ W2, const float* __restrict__ W3,
                            const float* __restrict__ W4, const float* __restrict__ b4,
                            float* __restrict__ Wt, float* __restrict__ b4p) {
    const int d = blockIdx.x * blockDim.x + threadIdx.x;
    if (d < NTILES * 1024) {
        const int t = d >> 10, w = d & 1023;
        float v;
        if (t < 52) {
            const int r = w >> 7, rem = w & 127;
            const int half = rem >> 6, q = (rem >> 2) & 15, jl = rem & 3;
            const int col = q * 8 + half * 4 + jl;
            if (t < 4)       { const int k = t * 8 + r;        v = (k < 27) ? W0[k * 128 + col] : 0.f; }
            else if (t < 20) { const int k = (t - 4) * 8 + r;  v = W1[k * 128 + col]; }
            else if (t < 36) { const int k = (t - 20) * 8 + r; v = W2[k * 128 + col]; }
            else             { const int k = (t - 36) * 8 + r; v = W3[k * 128 + col]; }
        } else {
            const int r = w >> 5, rem = w & 31;
            const int half = (rem >> 4) & 1, s = (rem >> 2) & 3, jl = rem & 3;
            const int col = s * 8 + half * 4 + jl;
            const int k = (t - 52) * 32 + r;
            v = (col < 25) ? W4[k * 25 + col] : 0.f;
        }
        Wt[d] = v;
    }
    if (d < 32) b4p[d] = (d < 25) ? b4[d] : 0.f;
}

// 4-row FMA batch, weights from LDS tile (rows r0..r0+3), h from LDS
__device__ __forceinline__ void batch4(const float* wt, int r0, int cg,
                                       const float* hg, int k0,
                                       v2f* __restrict__ acc) {
    float4 h4[4];
#pragma unroll
    for (int p = 0; p < 4; ++p) h4[p] = *(const float4*)(hg + p * HP + k0);
    float4 w0[4], w1[4];
#pragma unroll
    for (int r = 0; r < 4; ++r) {
        w0[r] = *(const float4*)(wt + (r0 + r) * 128 + cg * 4);
        w1[r] = *(const float4*)(wt + (r0 + r) * 128 + 64 + cg * 4);
    }
#pragma unroll
    for (int r = 0; r < 4; ++r) {
        const v2f wa = mkv2(w0[r].x, w0[r].y), wb2 = mkv2(w0[r].z, w0[r].w);
        const v2f wc = mkv2(w1[r].x, w1[r].y), wd = mkv2(w1[r].z, w1[r].w);
#pragma unroll
        for (int p = 0; p < 4; ++p) {
            const float hv = f4el(h4[p], r);
            const v2f hh = mkv2(hv, hv);
            acc[p * 4 + 0] = pkfma(hh, wa, acc[p * 4 + 0]);
            acc[p * 4 + 1] = pkfma(hh, wb2, acc[p * 4 + 1]);
            acc[p * 4 + 2] = pkfma(hh, wc, acc[p * 4 + 2]);
            acc[p * 4 + 3] = pkfma(hh, wd, acc[p * 4 + 3]);
        }
    }
}

// LDS state slots: 0..8 J, 9..11 up, 12..14 dx, 15..17 dg, 18..20 xo,
// 21 nopt, 22..24 rw (cached tf(xopt)·xopt+off -> no final eval)
__global__ __launch_bounds__(BLOCK)
__attribute__((amdgpu_num_vgpr(128))) void snarf_kernel(
    const float* __restrict__ xin, const float* __restrict__ bone_pts,
    const float* __restrict__ transforms, const float* __restrict__ delta_tf,
    const float* __restrict__ Wt, const float* __restrict__ b0,
    const float* __restrict__ b1, const float* __restrict__ b2,
    const float* __restrict__ b3, const float* __restrict__ b4p,
    float* __restrict__ out, int Npts) {
    __shared__ float hL[4 * WCOLS];   // 34176 B swizzled h[prob][k]
    __shared__ float stL[25 * PPB];   // 6400 B solver state
    __shared__ float wb[2][1024];     // 8192 B weight tile double-buffer
    __shared__ int flags[4];          // (total 48784 B)
    const int tid = threadIdx.x;
    const int wid = tid >> 6;
    const int lane = tid & 63;
    const int p16 = lane & 15;
    const int sq = lane >> 4;
    const int cg = lane >> 2;
    const int gg = lane & 3;
    const int M = Npts * 6;
    const int m = blockIdx.x * PPB + wid * 16 + p16;
    const int mc = (m < M) ? m : (M - 1);
    const int n = mc / 6;
    const int i = mc - n * 6;

    float* hWv = &hL[wid * WCOLS];
    const float* hg = hWv + gg * 536;
    float* hwr = hWv + gg * 536 + 8 * cg;
    float* hq = hWv + col_base(p16);
    volatile float* st = &stL[wid * 16 + p16];
#define STS(idx) st[(idx) * PPB]

    const float tx = xin[n * 3 + 0], ty = xin[n * 3 + 1], tz = xin[n * 3 + 2];

    // ---- init candidate (duplicated across sq; bitwise identical)
    float xk0, xk1, xk2;
    if (i < 5) {
        float dprev = -1.0f;
        int jprev = -1;
        for (int r = 0; r <= i; ++r) {
            float bd = 3.4028235e38f;
            int bj = 0;
            for (int j = 0; j < 24; ++j) {
                const float ax = tx - bone_pts[j * 3 + 0];
                const float ay = ty - bone_pts[j * 3 + 1];
                const float az = tz - bone_pts[j * 3 + 2];
                const float d = sqrtf(ax * ax + ay * ay + az * az);
                const bool taken = (d < dprev) || (d == dprev && j <= jprev);
                if (!taken && d < bd) { bd = d; bj = j; }
            }
            dprev = bd;
            jprev = bj;
        }
        const float* T = delta_tf + jprev * 16;
        xk0 = fmaf(T[0], tx, fmaf(T[1], ty, fmaf(T[2], tz, T[3])));
        xk1 = fmaf(T[4], tx, fmaf(T[5], ty, fmaf(T[6], tz, T[7])));
        xk2 = fmaf(T[8], tx, fmaf(T[9], ty, fmaf(T[10], tz, T[11])));
    } else {
        xk0 = tx; xk1 = ty; xk2 = tz;
    }

    float gx0 = 0.f, gx1 = 0.f, gx2 = 0.f;
    bool mask = (m < M);

    // stage tile 0 into buf 0 (register round-trip staging)
    int cur = 0;
    *(float4*)(&wb[0][0] + tid * 4) = *(const float4*)(Wt + tid * 4);
    __syncthreads();

    for (int step = -1; step < 8; ++step) {
        bool m3 = mask;
        if (step >= 0) {
            __syncthreads();
            if ((flags[0] | flags[1] | flags[2] | flags[3]) == 0) break;
            if (m3) {
                const float u0 = STS(9), u1 = STS(10), u2 = STS(11);
                STS(12) = u0; STS(13) = u1; STS(14) = u2;
                xk0 += u0; xk1 += u1; xk2 += u2;
            }
        }

        // wave-skip: fully-converged wave keeps barrier/staging lockstep
        // (same staged-tile sequence 1..55,0 and same 56 barriers) but no math
        if (__ballot(mask) == 0ull) {
#pragma unroll 1
            for (int t = 0; t < NTILES; ++t) {
                const int nt = (t + 1 < NTILES) ? (t + 1) : 0;
                const float4 stg = *(const float4*)(Wt + nt * 1024 + tid * 4);
                *(float4*)(&wb[cur ^ 1][0] + tid * 4) = stg;
                __syncthreads();
                cur ^= 1;
            }
            if (lane == 0) flags[wid] = 0;
            continue;
        }

        const float cx0 = xk0, cx1 = xk1, cx2 = xk2;

        // ---- positional encoding, split by scale (sq owns scale 1<<sq), HW trig
        {
            const float f = (float)(1 << sq);
            float sx, cxv, sy, cyv, sz, czv;
            __sincosf(f * cx0, &sx, &cxv);
            __sincosf(f * cx1, &sy, &cyv);
            __sincosf(f * cx2, &sz, &czv);
            if (sq == 0) { hq[0] = cx0; hq[1] = cx1; hq[2] = cx2; }
            const int sb = 3 + sq * 3;
            hq[sb + 0] = sx;  hq[sb + 1] = sy;  hq[sb + 2] = sz;
            hq[sb + 12] = cxv; hq[sb + 13] = cyv; hq[sb + 14] = czv;
            if (sq == 3) {
                hq[27] = 0.f; hq[28] = 0.f; hq[29] = 0.f; hq[30] = 0.f; hq[31] = 0.f;
            }
        }

        __builtin_amdgcn_s_setprio(1);
        int gt = 0;  // tile id within this eval (0..55)
        // ---- 4 main layers from LDS tiles (tiles 0..51)
#pragma unroll 1
        for (int L = 0; L < 4; ++L) {
            const int NT = (L == 0) ? 4 : 16;
            const float* bc = ((L == 0) ? b0 : (L == 1) ? b1 : (L == 2) ? b2 : b3) + 8 * cg;
            v2f acc[16];
            {
                const float4 b0v = *(const float4*)(bc);
                const float4 b1v = *(const float4*)(bc + 4);
#pragma unroll
                for (int p = 0; p < 4; ++p) {
                    acc[p * 4 + 0] = mkv2(b0v.x, b0v.y);
                    acc[p * 4 + 1] = mkv2(b0v.z, b0v.w);
                    acc[p * 4 + 2] = mkv2(b1v.x, b1v.y);
                    acc[p * 4 + 3] = mkv2(b1v.z, b1v.w);
                }
            }
#pragma unroll 1
            for (int t = 0; t < NT; ++t) {
                // async-stage: load next tile early (regs), write to LDS late
                const float4 stg = *(const float4*)(Wt + (gt + 1) * 1024 + tid * 4);
                batch4(&wb[cur][0], 0, cg, hg, t * 8, acc);
                batch4(&wb[cur][0], 4, cg, hg, t * 8 + 4, acc);
                *(float4*)(&wb[cur ^ 1][0] + tid * 4) = stg;
                __syncthreads();
                cur ^= 1;
                ++gt;
            }
            // writeback (static p order)
#pragma unroll
            for (int p = 0; p < 4; ++p) {
                float4 o0, o1;
                o0.x = fmaxf(acc[p * 4 + 0].x, 0.f); o0.y = fmaxf(acc[p * 4 + 0].y, 0.f);
                o0.z = fmaxf(acc[p * 4 + 1].x, 0.f); o0.w = fmaxf(acc[p * 4 + 1].y, 0.f);
                o1.x = fmaxf(acc[p * 4 + 2].x, 0.f); o1.y = fmaxf(acc[p * 4 + 2].y, 0.f);
                o1.z = fmaxf(acc[p * 4 + 3].x, 0.f); o1.w = fmaxf(acc[p * 4 + 3].y, 0.f);
                *(float4*)(hwr + p * HP) = o0;
                *(float4*)(hwr + p * HP + 4) = o1;
            }
        }

        // ---- output layer: tiles 52..55 (32 rows x 32 permuted cols each)
        {
            v2f la[4];
            const float4 bb0 = *(const float4*)(b4p + 8 * sq);
            const float4 bb1 = *(const float4*)(b4p + 8 * sq + 4);
            la[0] = mkv2(bb0.x, bb0.y); la[1] = mkv2(bb0.z, bb0.w);
            la[2] = mkv2(bb1.x, bb1.y); la[3] = mkv2(bb1.z, bb1.w);
#pragma unroll 1
            for (int t = 0; t < 4; ++t) {
                const int nt = (t < 3) ? (53 + t) : 0;  // wrap: last stages tile 0
                const float4 stg = *(const float4*)(Wt + nt * 1024 + tid * 4);
                const float* wt = &wb[cur][0];
#pragma unroll 2
                for (int kb = 0; kb < 8; ++kb) {
                    const float4 h4 = *(const float4*)(hq + t * 32 + kb * 4);
#pragma unroll
                    for (int r = 0; r < 4; ++r) {
                        const float4 w0 = *(const float4*)(wt + (kb * 4 + r) * 32 + sq * 4);
                        const float4 w1 = *(const float4*)(wt + (kb * 4 + r) * 32 + 16 + sq * 4);
                        const float hv = f4el(h4, r);
                        const v2f hh = mkv2(hv, hv);
                        la[0] = pkfma(hh, mkv2(w0.x, w0.y), la[0]);
                        la[1] = pkfma(hh, mkv2(w0.z, w0.w), la[1]);
                        la[2] = pkfma(hh, mkv2(w1.x, w1.y), la[2]);
                        la[3] = pkfma(hh, mkv2(w1.z, w1.w), la[3]);
                    }
                }
                *(float4*)(&wb[cur ^ 1][0] + tid * 4) = stg;
                __syncthreads();
                cur ^= 1;
            }
            __builtin_amdgcn_s_setprio(0);
            float4 o0, o1;
            o0.x = la[0].x; o0.y = la[0].y; o0.z = la[1].x; o0.w = la[1].y;
            o1.x = la[2].x; o1.y = la[2].y; o1.z = la[3].x; o1.w = la[3].y;
            *(float4*)(hq + 8 * sq) = o0;
            *(float4*)(hq + 8 * sq + 4) = o1;
        }

        // ---- read 25 logits (dup x4)
        float l25[25];
        {
            const float4 r0 = *(const float4*)(hq + 0);
            const float4 r1 = *(const float4*)(hq + 4);
            const float4 r2 = *(const float4*)(hq + 8);
            const float4 r3 = *(const float4*)(hq + 12);
            const float4 r4 = *(const float4*)(hq + 16);
            const float4 r5 = *(const float4*)(hq + 20);
            l25[0] = r0.x; l25[1] = r0.y; l25[2] = r0.z; l25[3] = r0.w;
            l25[4] = r1.x; l25[5] = r1.y; l25[6] = r1.z; l25[7] = r1.w;
            l25[8] = r2.x; l25[9] = r2.y; l25[10] = r2.z; l25[11] = r2.w;
            l25[12] = r3.x; l25[13] = r3.y; l25[14] = r3.z; l25[15] = r3.w;
            l25[16] = r4.x; l25[17] = r4.y; l25[18] = r4.z; l25[19] = r4.w;
            l25[20] = r5.x; l25[21] = r5.y; l25[22] = r5.z; l25[23] = r5.w;
            l25[24] = hq[24];
        }

        // softmax(5 * logits) over 25, HW exp
        float zm = -3.4028235e38f;
#pragma unroll
        for (int j = 0; j < 25; ++j) {
            l25[j] = 5.0f * l25[j];
            zm = fmaxf(zm, l25[j]);
        }
        float ssum = 0.f;
#pragma unroll
        for (int j = 0; j < 25; ++j) {
            l25[j] = __expf(l25[j] - zm);
            ssum += l25[j];
        }
        const float inv = 1.0f / ssum;

        // ---- blend: packed accumulate of 12 tf entries with UNNORMALIZED
        // weights; normalization (inv) folded into the final 3 results
        v2f e01 = mkv2(0.f, 0.f), e23 = mkv2(0.f, 0.f);
        v2f e45 = mkv2(0.f, 0.f), e67 = mkv2(0.f, 0.f);
        v2f e89 = mkv2(0.f, 0.f), eAB = mkv2(0.f, 0.f);
#pragma unroll
        for (int j = 0; j < 24; ++j) {
            const float wj = l25[j];
            const v2f ww = mkv2(wj, wj);
            const float4 T0 = *(const float4*)(transforms + j * 16);
            const float4 T1 = *(const float4*)(transforms + j * 16 + 4);
            const float4 T2 = *(const float4*)(transforms + j * 16 + 8);
            e01 = pkfma(ww, mkv2(T0.x, T0.y), e01);
            e23 = pkfma(ww, mkv2(T0.z, T0.w), e23);
            e45 = pkfma(ww, mkv2(T1.x, T1.y), e45);
            e67 = pkfma(ww, mkv2(T1.z, T1.w), e67);
            e89 = pkfma(ww, mkv2(T2.x, T2.y), e89);
            eAB = pkfma(ww, mkv2(T2.z, T2.w), eAB);
        }
        {
            const float wj = l25[24];  // identity transform diag (0,5,10)
            e01.x += wj; e45.y += wj; eAB.x += wj;
        }
        const float r0 = fmaf(e01.x, cx0, fmaf(e01.y, cx1, fmaf(e23.x, cx2, e23.y))) * inv;
        const float r1 = fmaf(e45.x, cx0, fmaf(e45.y, cx1, fmaf(e67.x, cx2, e67.y))) * inv;
        const float r2 = fmaf(e89.x, cx0, fmaf(e89.y, cx1, fmaf(eAB.x, cx2, eAB.y))) * inv;

        const float g0 = r0 - tx, g1 = r1 - ty, g2 = r2 - tz;

        if (step == -1) {
            gx0 = g0; gx1 = g1; gx2 = g2;
            const float gn = sqrtf(g0 * g0 + g1 * g1 + g2 * g2);
            STS(21) = gn;
            STS(9) = -g0; STS(10) = -g1; STS(11) = -g2;
            STS(18) = xk0; STS(19) = xk1; STS(20) = xk2;
            STS(22) = r0; STS(23) = r1; STS(24) = r2;
            STS(12) = 0.f; STS(13) = 0.f; STS(14) = 0.f;
            STS(15) = 0.f; STS(16) = 0.f; STS(17) = 0.f;
            STS(0) = 1.f; STS(1) = 0.f; STS(2) = 0.f;
            STS(3) = 0.f; STS(4) = 1.f; STS(5) = 0.f;
            STS(6) = 0.f; STS(7) = 0.f; STS(8) = 1.f;
        } else {
            float J00 = STS(0), J01 = STS(1), J02 = STS(2);
            float J10 = STS(3), J11 = STS(4), J12 = STS(5);
            float J20 = STS(6), J21 = STS(7), J22 = STS(8);
            const float dx0 = STS(12), dx1 = STS(13), dx2 = STS(14);
            float dg0 = STS(15), dg1 = STS(16), dg2 = STS(17);
            float nopt = STS(21);
            if (m3) {
                dg0 = g0 - gx0; dg1 = g1 - gx1; dg2 = g2 - gx2;
                gx0 += dg0; gx1 += dg1; gx2 += dg2;
                STS(15) = dg0; STS(16) = dg1; STS(17) = dg2;
            }
            const float gn = sqrtf(gx0 * gx0 + gx1 * gx1 + gx2 * gx2);
            const bool better = gn < nopt;
            if (better) {
                nopt = gn;
                STS(21) = gn;
                STS(18) = xk0; STS(19) = xk1; STS(20) = xk2;
                STS(22) = r0; STS(23) = r1; STS(24) = r2;
            }
            mask = (nopt > 1e-5f) && (gn < 1.0f) && (m < M);

            const float v0 = dx0 * J00 + dx1 * J10 + dx2 * J20;
            const float v1 = dx0 * J01 + dx1 * J11 + dx2 * J21;
            const float v2 = dx0 * J02 + dx1 * J12 + dx2 * J22;
            const float Jd0 = J00 * dg0 + J01 * dg1 + J02 * dg2;
            const float Jd1 = J10 * dg0 + J11 * dg1 + J12 * dg2;
            const float Jd2 = J20 * dg0 + J21 * dg1 + J22 * dg2;
            const float a0 = dx0 - Jd0, a1 = dx1 - Jd1, a2 = dx2 - Jd2;
            float bden = v0 * dg0 + v1 * dg1 + v2 * dg2;
            bden += (bden >= 0.f) ? 1e-6f : -1e-6f;
            if (mask) {
                const float q0 = a0 / bden, q1 = a1 / bden, q2 = a2 / bden;
                J00 = fmaf(q0, v0, J00); J01 = fmaf(q0, v1, J01); J02 = fmaf(q0, v2, J02);
                J10 = fmaf(q1, v0, J10); J11 = fmaf(q1, v1, J11); J12 = fmaf(q1, v2, J12);
                J20 = fmaf(q2, v0, J20); J21 = fmaf(q2, v1, J21); J22 = fmaf(q2, v2, J22);
                STS(0) = J00; STS(1) = J01; STS(2) = J02;
                STS(3) = J10; STS(4) = J11; STS(5) = J12;
                STS(6) = J20; STS(7) = J21; STS(8) = J22;
            }
            if (m3) {
                STS(9) = -(J00 * gx0 + J01 * gx1 + J02 * gx2);
                STS(10) = -(J10 * gx0 + J11 * gx1 + J12 * gx2);
                STS(11) = -(J20 * gx0 + J21 * gx1 + J22 * gx2);
            }
        }
        // block-exit flags (read after the barrier at next eval top)
        {
            const unsigned long long b = __ballot(mask);
            if (lane == 0) flags[wid] = (b != 0ull) ? 1 : 0;
        }
    }

    // ---- epilogue: all outputs from cached state (no final eval)
    if (sq == 0 && m < M) {
        const float nopt = STS(21);
        out[(size_t)m * 3 + 0] = STS(22);
        out[(size_t)m * 3 + 1] = STS(23);
        out[(size_t)m * 3 + 2] = STS(24);
        float* xopt_out = out + (size_t)M * 3;
        xopt_out[(size_t)m * 3 + 0] = STS(18);
        xopt_out[(size_t)m * 3 + 1] = STS(19);
        xopt_out[(size_t)m * 3 + 2] = STS(20);
        out[(size_t)M * 6 + m] = nopt;
        out[(size_t)M * 7 + m] = (nopt < 1e-5f) ? 1.0f : 0.0f;
    }
#undef STS
}

extern "C" void kernel_launch(void* const* d_in, const int* in_sizes, int n_in,
                              void* d_out, int out_size, void* d_ws, size_t ws_size,
                              hipStream_t stream) {
    const float* x = (const float*)d_in[0];
    const float* bone_pts = (const float*)d_in[1];
    const float* transforms = (const float*)d_in[2];
    const float* delta_tf = (const float*)d_in[3];
    const float* W0 = (const float*)d_in[4];
    const float* b0 = (const float*)d_in[5];
    const float* W1 = (const float*)d_in[6];
    const float* b1 = (const float*)d_in[7];
    const float* W2 = (const float*)d_in[8];
    const float* b2 = (const float*)d_in[9];
    const float* W3 = (const float*)d_in[10];
    const float* b3 = (const float*)d_in[11];
    const float* W4 = (const float*)d_in[12];
    const float* b4 = (const float*)d_in[13];
    float* out = (float*)d_out;

    float* Wt = (float*)d_ws;          // 56*1024 floats (tiled weights)
    float* b4p = Wt + NTILES * 1024;   // 32 floats

    prep_kernel<<<(NTILES * 1024 + 255) / 256, 256, 0, stream>>>(
        W0, W1, W2, W3, W4, b4, Wt, b4p);

    const int Npts = in_sizes[0] / 3;
    const int M = Npts * 6;
    const int blocks = (M + PPB - 1) / PPB;
    snarf_kernel<<<blocks, BLOCK, 0, stream>>>(
        x, bone_pts, transforms, delta_tf, Wt, b0, b1, b2, b3, b4p, out, Npts);
}